// Round 1
// 868.399 us; speedup vs baseline: 1.0593x; 1.0593x over previous
//
#include <hip/hip_runtime.h>

// TT-LSTM: B=64, T=1024, D=H=256, F=16, R=16, NG=4.
// ws layout (floats):
//   A1ihT [64][256]  @ 0       ([g*16+s][m*16+n], composed g0*g1 for ih)
//   A1hT  [64][256]  @ 16384   (same for hh)
//   C2ih  [64][256]  @ 32768   ([g*16+s][o*16+p], composed g2*g3 for ih)
//   C2h   [64][256]  @ 49152
//   biasS [4][256]   @ 65536   (ih_bias + hh_bias)
//   T2ih  [65536][64]@ 66560   (first-stage ih contraction for all rows)

#define WS_A1I 0
#define WS_A1H 16384
#define WS_C2I 32768
#define WS_C2H 49152
#define WS_BIAS 65536
#define WS_T2 66560

typedef float v2f __attribute__((ext_vector_type(2)));

// Packed fp32 FMA: 2 FMAs/instruction (the only path to gfx950's 157 TF fp32).
// Non-volatile asm so the scheduler can still move it.
__device__ __forceinline__ v2f pk_fma(v2f a, v2f b, v2f c) {
    v2f d;
    asm("v_pk_fma_f32 %0, %1, %2, %3" : "=v"(d) : "v"(a), "v"(b), "v"(c));
    return d;
}

// Barrier draining LDS only (lgkmcnt), NOT global loads/stores (vmcnt).
__device__ __forceinline__ void bar_lds() {
    asm volatile("s_waitcnt lgkmcnt(0)\n\ts_barrier" ::: "memory");
}

// DPP helpers: cross-lane at VALU rate (no DS pipe). dpp_ctrl must be an
// immediate -> template parameter.
// row_shr:n = 0x110|n ; quad_perm(k,k,k,k) = k*0x55. bound_ctrl=1 -> 0 fill.
template <int CTRL>
__device__ __forceinline__ float dpp_add(float v) {
    int s = __builtin_amdgcn_update_dpp(0, __float_as_int(v), CTRL, 0xF, 0xF, true);
    return v + __int_as_float(s);
}
template <int CTRL>
__device__ __forceinline__ float dpp_bcast(float v) {
    int s = __builtin_amdgcn_update_dpp(0, __float_as_int(v), CTRL, 0xF, 0xF, true);
    return __int_as_float(s);
}

// ---------------- K0: compose TT cores ----------------
__global__ void k_compose(const float* __restrict__ g0i, const float* __restrict__ g1i,
                          const float* __restrict__ g2i, const float* __restrict__ g3i,
                          const float* __restrict__ bi,
                          const float* __restrict__ g0h, const float* __restrict__ g1h,
                          const float* __restrict__ g2h, const float* __restrict__ g3h,
                          const float* __restrict__ bh,
                          float* __restrict__ ws) {
    int id = blockIdx.x * 256 + threadIdx.x;
    if (id < 16384) {
        int g = id >> 12, s = (id >> 8) & 15, mn = id & 255;
        int m = mn >> 4, n = mn & 15;
        float aI = 0.f, aH = 0.f;
        for (int r = 0; r < 16; ++r) {
            aI += g0i[(g * 16 + m) * 16 + r] * g1i[((g * 16 + r) * 16 + n) * 16 + s];
            aH += g0h[(g * 16 + m) * 16 + r] * g1h[((g * 16 + r) * 16 + n) * 16 + s];
        }
        ws[WS_A1I + (g * 16 + s) * 256 + mn] = aI;
        ws[WS_A1H + (g * 16 + s) * 256 + mn] = aH;
    } else if (id < 32768) {
        int id2 = id - 16384;
        int g = id2 >> 12, s = (id2 >> 8) & 15, j = id2 & 255;
        int o = j >> 4, p = j & 15;
        float aI = 0.f, aH = 0.f;
        for (int t = 0; t < 16; ++t) {
            aI += g2i[((g * 16 + s) * 16 + o) * 16 + t] * g3i[(g * 16 + t) * 16 + p];
            aH += g2h[((g * 16 + s) * 16 + o) * 16 + t] * g3h[(g * 16 + t) * 16 + p];
        }
        ws[WS_C2I + (g * 16 + s) * 256 + j] = aI;
        ws[WS_C2H + (g * 16 + s) * 256 + j] = aH;
    } else if (id < 33792) {
        int id2 = id - 32768;
        ws[WS_BIAS + id2] = bi[id2] + bh[id2];
    }
}

// ---------------- K1: T2ih = X @ A1ih ----------------
// Rework vs r0-prev:
//  - K split into 2x128 tiles: LDS 64KB -> 2 blocks/CU (was 128KB -> 1),
//    2 waves/SIMD hide ds latency.
//  - Swizzle col = c ^ (row>>2): compute reads stride rows by 4, so row>>2
//    (=ro or q) varies across the 16 addresses of one ds_read_b128 ->
//    2-way (free). The old c ^ (row&15) collapsed to 2 bank-quads = 8-way.
//  - v_pk_fma_f32: 64 scalar FMA/iter -> 32 packed.
__global__ __launch_bounds__(256, 2) void k_t2ih(const float* __restrict__ x,
                                                 const float* __restrict__ ws,
                                                 float* __restrict__ T2) {
    __shared__ __align__(16) float Xs[64 * 128];
    __shared__ __align__(16) float As[64 * 128];
    const int tid = threadIdx.x;
    const long r0 = (long)blockIdx.x * 64;
    const int ro = tid & 15;
    const int q  = tid >> 4;

    const float4* X4g = (const float4*)x;            // row stride 64 float4
    const float4* A4  = (const float4*)(ws + WS_A1I);
    float4* Xs4 = (float4*)Xs;                       // 32 float4 per row
    float4* As4 = (float4*)As;

    v2f acc2[4][4];
#pragma unroll
    for (int i = 0; i < 4; ++i)
#pragma unroll
        for (int j = 0; j < 4; ++j) acc2[i][j] = (v2f){0.f, 0.f};

    for (int half = 0; half < 2; ++half) {
        __syncthreads();  // WAR vs previous half's reads (no-op cost at half=0)
#pragma unroll
        for (int k = 0; k < 8; ++k) {
            int idx = k * 256 + tid;                 // 0..2047
            int row = idx >> 5, c = idx & 31;
            int sw = (row << 5) | (c ^ ((row >> 2) & 15));
            Xs4[sw] = X4g[(r0 + row) * 64 + half * 32 + c];
            As4[sw] = A4[row * 64 + half * 32 + c];
        }
        __syncthreads();

#pragma unroll 4
        for (int mn4 = 0; mn4 < 32; ++mn4) {
            float4 a[4], xv[4];
#pragma unroll
            for (int j = 0; j < 4; ++j) {
                int row = ro * 4 + j;                // row>>2 == ro
                a[j] = As4[(row << 5) | (mn4 ^ ro)];
            }
#pragma unroll
            for (int i = 0; i < 4; ++i) {
                int row = q * 4 + i;                 // row>>2 == q
                xv[i] = Xs4[(row << 5) | (mn4 ^ q)];
            }
#pragma unroll
            for (int i = 0; i < 4; ++i)
#pragma unroll
                for (int j = 0; j < 4; ++j) {
                    acc2[i][j] = pk_fma((v2f){xv[i].x, xv[i].y},
                                        (v2f){a[j].x, a[j].y}, acc2[i][j]);
                    acc2[i][j] = pk_fma((v2f){xv[i].z, xv[i].w},
                                        (v2f){a[j].z, a[j].w}, acc2[i][j]);
                }
        }
    }
#pragma unroll
    for (int i = 0; i < 4; ++i)
#pragma unroll
        for (int j = 0; j < 4; ++j)
            T2[(r0 + q * 4 + i) * 64 + ro * 4 + j] = acc2[i][j].x + acc2[i][j].y;
}

// ---------------- K2: recurrent LSTM ----------------
// 64 blocks x 1024 threads (16 waves, 4/SIMD), 1024 steps, 2 barriers/step.
// ZERO DS-pipe cross-lane ops: reductions/gathers via DPP (VALU rate).
// This round: AB 16 FMA -> 8 v_pk_fma_f32; CD 32 FMA -> 16 v_pk_fma_f32
// (two interleaved packed accumulator chains, dep distance 2 inst).
// hS transposed layout unchanged: float4 slot kk*16+sub = h[16*sub+4*kk..+3]
// -> AB reads bank-base 4*sub mod 32 = true 2-way (free).
__global__ __launch_bounds__(1024, 4) void k_lstm(const float* __restrict__ ws,
                                                  const float* __restrict__ T2,
                                                  float* __restrict__ out) {
    __shared__ __align__(16) float hS[256];
    __shared__ __align__(16) float t2hS[64];
    __shared__ __align__(16) float t2iS[2][64];

    const int tid  = threadIdx.x;
    const int w    = tid >> 6;
    const int lane = tid & 63;
    const int b    = blockIdx.x;

    // ---- AB weights: a1p[8] (v2f pairs) = A1h[u][sub*16 .. sub*16+16) ----
    const int uab = 4 * w + (lane >> 4);
    const int sub = lane & 15;
    v2f a1p[8];
    {
        const float4* A1h4 = (const float4*)(ws + WS_A1H);
#pragma unroll
        for (int kk = 0; kk < 4; ++kk) {
            float4 v = A1h4[uab * 64 + sub * 4 + kk];
            a1p[2 * kk + 0] = (v2f){v.x, v.y};
            a1p[2 * kk + 1] = (v2f){v.z, v.w};
        }
    }

    // ---- CD weights: jj=lane>>2, gate g=lane&3, hidden j=16w+jj ----
    const int jj = lane >> 2;
    const int g  = lane & 3;
    const int j  = 16 * w + jj;
    v2f c2hp[8], c2ip[8];
#pragma unroll
    for (int qq = 0; qq < 4; ++qq) {
        float h0 = ws[WS_C2H + (16 * g + 4 * qq + 0) * 256 + j];
        float h1 = ws[WS_C2H + (16 * g + 4 * qq + 1) * 256 + j];
        float h2 = ws[WS_C2H + (16 * g + 4 * qq + 2) * 256 + j];
        float h3 = ws[WS_C2H + (16 * g + 4 * qq + 3) * 256 + j];
        float i0 = ws[WS_C2I + (16 * g + 4 * qq + 0) * 256 + j];
        float i1 = ws[WS_C2I + (16 * g + 4 * qq + 1) * 256 + j];
        float i2 = ws[WS_C2I + (16 * g + 4 * qq + 2) * 256 + j];
        float i3 = ws[WS_C2I + (16 * g + 4 * qq + 3) * 256 + j];
        c2hp[2 * qq + 0] = (v2f){h0, h1};
        c2hp[2 * qq + 1] = (v2f){h2, h3};
        c2ip[2 * qq + 0] = (v2f){i0, i1};
        c2ip[2 * qq + 1] = (v2f){i2, i3};
    }
    float bias = ws[WS_BIAS + g * 256 + j];
    const float am = (g == 2) ? 2.0f : 1.0f;            // tanh vs sigmoid
    const float as = 1.442695040888963f * am;

#pragma unroll
    for (int i = 0; i < 8; ++i)
        asm volatile("" : "+v"(a1p[i]), "+v"(c2hp[i]), "+v"(c2ip[i]));

    // transposed hS slot for writer (g==0): word 64*(jj>>2) + 4*w + (jj&3)
    const int hw = ((jj >> 2) << 6) + (w << 2) + (jj & 3);

    float c = 0.f, h_last = 0.f;
    if (tid < 256) hS[tid] = 0.f;
    const float* T2b = T2 + (long)b * 1024 * 64;
    const float4* T2b4 = (const float4*)T2b;
    float4 preA = make_float4(0.f, 0.f, 0.f, 0.f);
    float4 preB = make_float4(0.f, 0.f, 0.f, 0.f);
    if (tid < 16) {
        ((float4*)t2iS[0])[tid] = T2b4[tid];
        preA = T2b4[16 + tid];                          // T2[t=1]
    }
    bar_lds();

    float* outB = out + (long)b * 1024 * 256;
    const float4* hS4 = (const float4*)hS;
    const float4* th4 = (const float4*)t2hS;

    auto body = [&](int t, float4& preW, float4& preL) {
        // ---- AB (packed) ----
        v2f sA = (v2f){0.f, 0.f}, sB = (v2f){0.f, 0.f};
#pragma unroll
        for (int kk = 0; kk < 4; ++kk) {
            float4 hv = hS4[kk * 16 + sub];             // 2-way bcast, free
            sA = pk_fma((v2f){hv.x, hv.y}, a1p[2 * kk + 0], sA);
            sB = pk_fma((v2f){hv.z, hv.w}, a1p[2 * kk + 1], sB);
        }
        float tv = (sA.x + sA.y) + (sB.x + sB.y);
        // stage next t2i + prefetch (independent; overlaps DPP chain)
        if ((tid < 16) && (t + 1 < 1024))
            ((float4*)t2iS[(t + 1) & 1])[tid] = preW;
        if ((tid < 16) && (t + 2 < 1024))
            preL = T2b4[(t + 2) * 16 + tid];
        // DPP sum over 16-lane row -> total in sub==15 (VALU rate)
        tv = dpp_add<0x111>(tv);   // row_shr:1
        tv = dpp_add<0x112>(tv);   // row_shr:2
        tv = dpp_add<0x114>(tv);   // row_shr:4
        tv = dpp_add<0x118>(tv);   // row_shr:8
        if (sub == 15) t2hS[uab] = tv;

        bar_lds();  // 1: t2hS + t2iS[(t+1)&1] ready

        // ---- CD + cell (packed, 2 interleaved chains) ----
        const float4* ti4 = (const float4*)t2iS[t & 1];
        v2f aH = (v2f){bias, 0.f}, aL = (v2f){0.f, 0.f};
#pragma unroll
        for (int qq = 0; qq < 4; ++qq) {
            float4 th = th4[g * 4 + qq];                // 2-way bcast, free
            float4 ti = ti4[g * 4 + qq];
            aH = pk_fma((v2f){th.x, th.y}, c2hp[2 * qq + 0], aH);
            aL = pk_fma((v2f){th.z, th.w}, c2hp[2 * qq + 1], aL);
            aH = pk_fma((v2f){ti.x, ti.y}, c2ip[2 * qq + 0], aH);
            aL = pk_fma((v2f){ti.z, ti.w}, c2ip[2 * qq + 1], aL);
        }
        float acc = (aH.x + aH.y) + (aL.x + aL.y);
        // unified activation: sigmoid(x)=1-1/(1+e^x), tanh(x)=1-2/(1+e^2x)
        float e   = __builtin_amdgcn_exp2f(as * acc);
        float act = 1.0f - am * __builtin_amdgcn_rcpf(1.0f + e);
        // gather i,f,g,o within the quad via DPP broadcasts
        float gi = dpp_bcast<0x00>(act);
        float gf = dpp_bcast<0x55>(act);
        float gg = dpp_bcast<0xAA>(act);
        float go = dpp_bcast<0xFF>(act);
        c = gf * c + gi * gg;
        float e2 = __builtin_amdgcn_exp2f(2.885390081777926f * c);
        float th_ = 1.0f - 2.0f * __builtin_amdgcn_rcpf(1.0f + e2);
        float h = go * th_;
        h_last = h;
        if (g == 0) {
            hS[hw] = h;                                 // 4-way write, ~free
            outB[t * 256 + j] = h;                      // never drained
        }

        bar_lds();  // 2: hS ready for next AB
    };

    for (int t = 0; t < 1024; t += 2) {
        body(t, preA, preB);
        body(t + 1, preB, preA);
    }

    if (g == 0) {
        out[16777216 + b * 256 + j] = h_last;
        out[16777216 + 16384 + b * 256 + j] = c;
    }
}

extern "C" void kernel_launch(void* const* d_in, const int* in_sizes, int n_in,
                              void* d_out, int out_size, void* d_ws, size_t ws_size,
                              hipStream_t stream) {
    const float* x     = (const float*)d_in[0];
    const float* ih_g0 = (const float*)d_in[1];
    const float* ih_g1 = (const float*)d_in[2];
    const float* ih_g2 = (const float*)d_in[3];
    const float* ih_g3 = (const float*)d_in[4];
    const float* ih_b  = (const float*)d_in[5];
    const float* hh_g0 = (const float*)d_in[6];
    const float* hh_g1 = (const float*)d_in[7];
    const float* hh_g2 = (const float*)d_in[8];
    const float* hh_g3 = (const float*)d_in[9];
    const float* hh_b  = (const float*)d_in[10];
    float* out = (float*)d_out;
    float* ws  = (float*)d_ws;

    k_compose<<<132, 256, 0, stream>>>(ih_g0, ih_g1, ih_g2, ih_g3, ih_b,
                                       hh_g0, hh_g1, hh_g2, hh_g3, hh_b, ws);
    k_t2ih<<<1024, 256, 0, stream>>>(x, ws, ws + WS_T2);
    k_lstm<<<64, 1024, 0, stream>>>(ws, ws + WS_T2, out);
}